// Round 2
// baseline (468.377 us; speedup 1.0000x reference)
//
#include <hip/hip_runtime.h>
#include <hip/hip_bf16.h>

typedef __hip_bfloat16 bf16;
typedef __attribute__((ext_vector_type(8))) short short8;
typedef __attribute__((ext_vector_type(4))) float floatx4;

#define BM 128
#define BN 128
#define BK 64

__device__ __forceinline__ void store_out(bf16* p, float v)  { *p = __float2bfloat16(v); }
__device__ __forceinline__ void store_out(float* p, float v) { *p = v; }

// C[M,N] = alpha * (A[M,K] . B[N,K]^T) + bias   (A,B bf16; C is OutT)
// bias_mode: 0 = none, 1 = bias[n] (per output col), 2 = bias[m] (per output row)
template <typename OutT>
__device__ __forceinline__ void gemm_bt_tile(
    const bf16* __restrict__ A, const bf16* __restrict__ B,
    const float* __restrict__ bias, OutT* __restrict__ C,
    int Kdim, int N, float alpha, int bm, int bn, int bias_mode)
{
    __shared__ __attribute__((aligned(16))) bf16 As[BM * BK];   // 16 KB
    __shared__ __attribute__((aligned(16))) bf16 Bs[BN * BK];   // 16 KB

    const int tid  = threadIdx.x;        // 0..255
    const int lane = tid & 63;
    const int wave = tid >> 6;           // 0..3
    const int wm   = (wave >> 1) << 6;   // wave row offset in block tile (0 / 64)
    const int wn   = (wave & 1) << 6;    // wave col offset (0 / 64)
    const int lr   = lane & 15;          // row-in-16 (A frag) / col-in-16 (B frag)
    const int lk   = (lane >> 4) << 3;   // which 8-of-32 k slice

    floatx4 acc[4][4] = {};

    const bf16* Ab = A + (size_t)(bm * BM) * Kdim;
    const bf16* Bb = B + (size_t)(bn * BN) * Kdim;

    for (int k0 = 0; k0 < Kdim; k0 += BK) {
        __syncthreads();  // previous tile's compute done before overwrite
#pragma unroll
        for (int p = 0; p < 4; ++p) {
            const int t   = p * 256 + tid;      // chunk id: 1024 chunks of 8 bf16
            const int row = t >> 3;             // 0..127
            const int c8  = (t & 7) << 3;       // 0..56
            __builtin_amdgcn_global_load_lds(
                (const __attribute__((address_space(1))) void*)(Ab + (size_t)row * Kdim + k0 + c8),
                (__attribute__((address_space(3))) void*)(As + t * 8), 16, 0, 0);
            __builtin_amdgcn_global_load_lds(
                (const __attribute__((address_space(1))) void*)(Bb + (size_t)row * Kdim + k0 + c8),
                (__attribute__((address_space(3))) void*)(Bs + t * 8), 16, 0, 0);
        }
        __syncthreads();  // implies s_waitcnt vmcnt(0): staging complete

#pragma unroll
        for (int kk = 0; kk < 2; ++kk) {
            short8 af[4], bfr[4];
#pragma unroll
            for (int i = 0; i < 4; ++i) {
                af[i]  = *(const short8*)(As + (wm + i * 16 + lr) * BK + kk * 32 + lk);
                bfr[i] = *(const short8*)(Bs + (wn + i * 16 + lr) * BK + kk * 32 + lk);
            }
#pragma unroll
            for (int i = 0; i < 4; ++i)
#pragma unroll
                for (int j = 0; j < 4; ++j)
                    acc[i][j] = __builtin_amdgcn_mfma_f32_16x16x32_bf16(
                        af[i], bfr[j], acc[i][j], 0, 0, 0);
        }
    }

    // Epilogue. C/D layout: col = lane&15, row = (lane>>4)*4 + reg   [m89-verified]
    const int rbase = (lane >> 4) << 2;
#pragma unroll
    for (int i = 0; i < 4; ++i) {
#pragma unroll
        for (int j = 0; j < 4; ++j) {
            const int n = bn * BN + wn + j * 16 + lr;
#pragma unroll
            for (int r = 0; r < 4; ++r) {
                const int m = bm * BM + wm + i * 16 + rbase + r;
                float v = acc[i][j][r] * alpha;
                if (bias_mode == 1)      v += bias[n];
                else if (bias_mode == 2) v += bias[m];
                store_out(&C[(size_t)m * N + n], v);
            }
        }
    }
}

// fp32 -> bf16 convert, 4 elems/thread, exact-sized grid (n % 4 == 0)
__global__ __launch_bounds__(256) void cvt_f32_bf16(
    const float* __restrict__ src, bf16* __restrict__ dst, int n4)
{
    const int i = blockIdx.x * 256 + threadIdx.x;
    if (i < n4) {
        const float4 v = ((const float4*)src)[i];
        bf16 o[4] = {__float2bfloat16(v.x), __float2bfloat16(v.y),
                     __float2bfloat16(v.z), __float2bfloat16(v.w)};
        ((ulong1*)dst)[i] = *(const ulong1*)o;
    }
}

// grid (32,16,3). z=0: Q = xb.Wqb^T + bq  [4096x2048]
//                 z=1: K = xb.Wkb^T + bk  [4096x2048]
//                 z=2: Vt = Wvb.xb^T + bv [2048x4096]  (V produced pre-transposed)
__global__ __launch_bounds__(256) void qkv_gemm(
    const bf16* __restrict__ xb,
    const bf16* __restrict__ Wqb, const float* __restrict__ bq,
    const bf16* __restrict__ Wkb, const float* __restrict__ bk,
    const bf16* __restrict__ Wvb, const float* __restrict__ bv,
    bf16* __restrict__ Q, bf16* __restrict__ Km, bf16* __restrict__ Vt)
{
    const int z = blockIdx.z;
    if (z == 0)
        gemm_bt_tile(xb, Wqb, bq, Q, 2048, 2048, 1.0f, blockIdx.x, blockIdx.y, 1);
    else if (z == 1)
        gemm_bt_tile(xb, Wkb, bk, Km, 2048, 2048, 1.0f, blockIdx.x, blockIdx.y, 1);
    else
        gemm_bt_tile(Wvb, xb, bv, Vt, 2048, 4096, 1.0f, blockIdx.y, blockIdx.x, 2);
}

// grid (32,32): S = (Q.K^T) / sqrt(2048)   [4096x4096], bf16 out
__global__ __launch_bounds__(256) void score_gemm(
    const bf16* __restrict__ Q, const bf16* __restrict__ Km, bf16* __restrict__ S)
{
    gemm_bt_tile(Q, Km, nullptr, S, 2048, 4096, 0.022097086912079608f,
                 blockIdx.x, blockIdx.y, 0);
}

// grid (32,16): out = S.(Vt)^T = S.V   [4096x2048], fp32 out
__global__ __launch_bounds__(256) void ctx_gemm(
    const bf16* __restrict__ S, const bf16* __restrict__ Vt, float* __restrict__ out)
{
    gemm_bt_tile(S, Vt, nullptr, out, 4096, 2048, 1.0f, blockIdx.x, blockIdx.y, 0);
}

extern "C" void kernel_launch(void* const* d_in, const int* in_sizes, int n_in,
                              void* d_out, int out_size, void* d_ws, size_t ws_size,
                              hipStream_t stream)
{
    const float* x  = (const float*)d_in[0];
    const float* Wq = (const float*)d_in[1];
    const float* bq = (const float*)d_in[2];
    const float* Wk = (const float*)d_in[3];
    const float* bk = (const float*)d_in[4];
    const float* Wv = (const float*)d_in[5];
    const float* bv = (const float*)d_in[6];
    float* out = (float*)d_out;

    const size_t ND = (size_t)4096 * 2048;   // x elems
    const size_t DD = (size_t)2048 * 2048;   // W elems

    // Workspace layout (bf16 elems):
    //  region A: xb(8M) Wqb(4M) Wkb(4M) Wvb(4M)  = 40 MB
    //  region B: Q(8M) K(8M) Vt(8M)              = 48 MB
    //  region C: S(16M)                           = 32 MB, reuses region A space? No:
    //  keep all live: 40 + 48 + 32 = 120 MB total
    bf16* xb  = (bf16*)d_ws;
    bf16* Wqb = xb  + ND;
    bf16* Wkb = Wqb + DD;
    bf16* Wvb = Wkb + DD;
    bf16* Q   = Wvb + DD;
    bf16* Km  = Q   + ND;
    bf16* Vt  = Km  + ND;
    bf16* S   = Vt  + ND;   // 4096*4096

    // fp32 -> bf16 converts (memory-bound, ~20 us total)
    cvt_f32_bf16<<<(int)(ND / 4 / 256), 256, 0, stream>>>(x,  xb,  (int)(ND / 4));
    cvt_f32_bf16<<<(int)(DD / 4 / 256), 256, 0, stream>>>(Wq, Wqb, (int)(DD / 4));
    cvt_f32_bf16<<<(int)(DD / 4 / 256), 256, 0, stream>>>(Wk, Wkb, (int)(DD / 4));
    cvt_f32_bf16<<<(int)(DD / 4 / 256), 256, 0, stream>>>(Wv, Wvb, (int)(DD / 4));

    qkv_gemm<<<dim3(32, 16, 3), 256, 0, stream>>>(xb, Wqb, bq, Wkb, bk, Wvb, bv, Q, Km, Vt);
    score_gemm<<<dim3(32, 32), 256, 0, stream>>>(Q, Km, S);
    ctx_gemm<<<dim3(32, 16), 256, 0, stream>>>(S, Vt, out);
}

// Round 3
// 401.674 us; speedup vs baseline: 1.1661x; 1.1661x over previous
//
#include <hip/hip_runtime.h>
#include <hip/hip_bf16.h>

typedef __hip_bfloat16 bf16;
typedef __attribute__((ext_vector_type(8))) short short8;
typedef __attribute__((ext_vector_type(4))) float floatx4;

#define BM 128
#define BN 128
#define BK 64

__device__ __forceinline__ void store_out(bf16* p, float v)  { *p = __float2bfloat16(v); }
__device__ __forceinline__ void store_out(float* p, float v) { *p = v; }

// C[M,N] = alpha * (A[M,K] . B[N,K]^T) + bias   (A,B bf16; C is OutT)
// bias_mode: 0 = none, 1 = bias[n] (per output col), 2 = bias[m] (per output row)
//
// LDS layout XOR-swizzled in 16-B chunks: slot (row, cs) holds global chunk
// cs ^ (row & 7). Staging permutes the per-lane GLOBAL address (LDS dest must
// stay lane-contiguous for global_load_lds); reads apply the inverse XOR.
// This spreads each quarter-wave ds_read_b128 across all 32 banks (was: 16
// lanes starting on ONE bank -> 2x LDS serialization, 3.8e7 conflicts/disp).
template <typename OutT>
__device__ __forceinline__ void gemm_bt_tile(
    const bf16* __restrict__ A, const bf16* __restrict__ B,
    const float* __restrict__ bias, OutT* __restrict__ C,
    int Kdim, int N, float alpha, int bm, int bn, int bias_mode)
{
    __shared__ __attribute__((aligned(16))) bf16 As[BM * BK];   // 16 KB
    __shared__ __attribute__((aligned(16))) bf16 Bs[BN * BK];   // 16 KB

    const int tid  = threadIdx.x;        // 0..255
    const int lane = tid & 63;
    const int wave = tid >> 6;           // 0..3
    const int wm   = (wave >> 1) << 6;   // wave row offset in block tile (0 / 64)
    const int wn   = (wave & 1) << 6;    // wave col offset (0 / 64)
    const int lr   = lane & 15;          // row-in-16 (A frag) / col-in-16 (B frag)
    const int lkc  = lane >> 4;          // k-chunk index 0..3 (8 bf16 = 16 B each)

    floatx4 acc[4][4] = {};

    const bf16* Ab = A + (size_t)(bm * BM) * Kdim;
    const bf16* Bb = B + (size_t)(bn * BN) * Kdim;

    for (int k0 = 0; k0 < Kdim; k0 += BK) {
        __syncthreads();  // previous tile's compute done before overwrite
#pragma unroll
        for (int p = 0; p < 4; ++p) {
            const int t   = p * 256 + tid;        // chunk id: 1024 chunks of 8 bf16
            const int row = t >> 3;               // 0..127
            const int cg  = (t & 7) ^ (row & 7);  // swizzled global chunk
            __builtin_amdgcn_global_load_lds(
                (const __attribute__((address_space(1))) void*)(Ab + (size_t)row * Kdim + k0 + cg * 8),
                (__attribute__((address_space(3))) void*)(As + t * 8), 16, 0, 0);
            __builtin_amdgcn_global_load_lds(
                (const __attribute__((address_space(1))) void*)(Bb + (size_t)row * Kdim + k0 + cg * 8),
                (__attribute__((address_space(3))) void*)(Bs + t * 8), 16, 0, 0);
        }
        __syncthreads();  // implies s_waitcnt vmcnt(0): staging complete

#pragma unroll
        for (int kk = 0; kk < 2; ++kk) {
            // inverse swizzle: want global chunk c = kk*4 + lkc of row r;
            // LDS slot = c ^ (r & 7); note r & 7 == lr & 7 for all fragments.
            const int sw = (((kk << 2) + lkc) ^ (lr & 7)) << 3;
            short8 af[4], bfr[4];
#pragma unroll
            for (int i = 0; i < 4; ++i) {
                af[i]  = *(const short8*)(As + (wm + i * 16 + lr) * BK + sw);
                bfr[i] = *(const short8*)(Bs + (wn + i * 16 + lr) * BK + sw);
            }
#pragma unroll
            for (int i = 0; i < 4; ++i)
#pragma unroll
                for (int j = 0; j < 4; ++j)
                    acc[i][j] = __builtin_amdgcn_mfma_f32_16x16x32_bf16(
                        af[i], bfr[j], acc[i][j], 0, 0, 0);
        }
    }

    // Epilogue. C/D layout: col = lane&15, row = (lane>>4)*4 + reg   [m89-verified]
    const int rbase = (lane >> 4) << 2;
#pragma unroll
    for (int i = 0; i < 4; ++i) {
#pragma unroll
        for (int j = 0; j < 4; ++j) {
            const int n = bn * BN + wn + j * 16 + lr;
#pragma unroll
            for (int r = 0; r < 4; ++r) {
                const int m = bm * BM + wm + i * 16 + rbase + r;
                float v = acc[i][j][r] * alpha;
                if (bias_mode == 1)      v += bias[n];
                else if (bias_mode == 2) v += bias[m];
                store_out(&C[(size_t)m * N + n], v);
            }
        }
    }
}

// Fused fp32 -> bf16 convert of x, Wq, Wk, Wv into one contiguous bf16 region.
// Dest layout: xb[ND] | Wqb[DD] | Wkb[DD] | Wvb[DD]; all sizes % 1024 == 0.
__global__ __launch_bounds__(256) void cvt_all(
    const float* __restrict__ x, const float* __restrict__ Wq,
    const float* __restrict__ Wk, const float* __restrict__ Wv,
    bf16* __restrict__ dst, int nd4, int dd4)
{
    const int i = blockIdx.x * 256 + threadIdx.x;   // float4 index
    const float* src;
    int off;
    if (i < nd4)                { src = x;  off = i; }
    else if (i < nd4 + dd4)     { src = Wq; off = i - nd4; }
    else if (i < nd4 + 2 * dd4) { src = Wk; off = i - nd4 - dd4; }
    else                        { src = Wv; off = i - nd4 - 2 * dd4; }
    const float4 v = ((const float4*)src)[off];
    bf16 o[4] = {__float2bfloat16(v.x), __float2bfloat16(v.y),
                 __float2bfloat16(v.z), __float2bfloat16(v.w)};
    ((ulong1*)dst)[i] = *(const ulong1*)o;
}

// grid (32,16,3). z=0: Q = xb.Wqb^T + bq  [4096x2048]
//                 z=1: K = xb.Wkb^T + bk  [4096x2048]
//                 z=2: Vt = Wvb.xb^T + bv [2048x4096]  (V produced pre-transposed)
__global__ __launch_bounds__(256) void qkv_gemm(
    const bf16* __restrict__ xb,
    const bf16* __restrict__ Wqb, const float* __restrict__ bq,
    const bf16* __restrict__ Wkb, const float* __restrict__ bk,
    const bf16* __restrict__ Wvb, const float* __restrict__ bv,
    bf16* __restrict__ Q, bf16* __restrict__ Km, bf16* __restrict__ Vt)
{
    const int z = blockIdx.z;
    if (z == 0)
        gemm_bt_tile(xb, Wqb, bq, Q, 2048, 2048, 1.0f, blockIdx.x, blockIdx.y, 1);
    else if (z == 1)
        gemm_bt_tile(xb, Wkb, bk, Km, 2048, 2048, 1.0f, blockIdx.x, blockIdx.y, 1);
    else
        gemm_bt_tile(Wvb, xb, bv, Vt, 2048, 4096, 1.0f, blockIdx.y, blockIdx.x, 2);
}

// grid (32,32): S = (Q.K^T) / sqrt(2048)   [4096x4096], bf16 out
__global__ __launch_bounds__(256) void score_gemm(
    const bf16* __restrict__ Q, const bf16* __restrict__ Km, bf16* __restrict__ S)
{
    gemm_bt_tile(Q, Km, nullptr, S, 2048, 4096, 0.022097086912079608f,
                 blockIdx.x, blockIdx.y, 0);
}

// grid (32,16): out = S.(Vt)^T = S.V   [4096x2048], fp32 out
__global__ __launch_bounds__(256) void ctx_gemm(
    const bf16* __restrict__ S, const bf16* __restrict__ Vt, float* __restrict__ out)
{
    gemm_bt_tile(S, Vt, nullptr, out, 4096, 2048, 1.0f, blockIdx.x, blockIdx.y, 0);
}

extern "C" void kernel_launch(void* const* d_in, const int* in_sizes, int n_in,
                              void* d_out, int out_size, void* d_ws, size_t ws_size,
                              hipStream_t stream)
{
    const float* x  = (const float*)d_in[0];
    const float* Wq = (const float*)d_in[1];
    const float* bq = (const float*)d_in[2];
    const float* Wk = (const float*)d_in[3];
    const float* bk = (const float*)d_in[4];
    const float* Wv = (const float*)d_in[5];
    const float* bv = (const float*)d_in[6];
    float* out = (float*)d_out;

    const size_t ND = (size_t)4096 * 2048;   // x elems
    const size_t DD = (size_t)2048 * 2048;   // W elems

    // Workspace (bf16 elems): xb(8M) Wqb Wkb Wvb(4M ea) Q K Vt(8M ea) S(16M) = 120 MB
    bf16* xb  = (bf16*)d_ws;
    bf16* Wqb = xb  + ND;
    bf16* Wkb = Wqb + DD;
    bf16* Wvb = Wkb + DD;
    bf16* Q   = Wvb + DD;
    bf16* Km  = Q   + ND;
    bf16* Vt  = Km  + ND;
    bf16* S   = Vt  + ND;   // 4096*4096

    const int nd4 = (int)(ND / 4), dd4 = (int)(DD / 4);
    cvt_all<<<(nd4 + 3 * dd4) / 256, 256, 0, stream>>>(x, Wq, Wk, Wv, xb, nd4, dd4);

    qkv_gemm<<<dim3(32, 16, 3), 256, 0, stream>>>(xb, Wqb, bq, Wkb, bk, Wvb, bv, Q, Km, Vt);
    score_gemm<<<dim3(32, 32), 256, 0, stream>>>(Q, Km, S);
    ctx_gemm<<<dim3(32, 16), 256, 0, stream>>>(S, Vt, out);
}

// Round 4
// 399.977 us; speedup vs baseline: 1.1710x; 1.0042x over previous
//
#include <hip/hip_runtime.h>
#include <hip/hip_bf16.h>

typedef __hip_bfloat16 bf16;
typedef __attribute__((ext_vector_type(8))) short short8;
typedef __attribute__((ext_vector_type(4))) float floatx4;

#define BK 64

__device__ __forceinline__ void store_out(bf16* p, float v)  { *p = __float2bfloat16(v); }
__device__ __forceinline__ void store_out(float* p, float v) { *p = v; }

// C[M,N] = alpha * (A[M,K] . B[N,K]^T) + bias   (A,B bf16; C is OutT)
// bias_mode: 0 = none, 1 = bias[n] (per output col), 2 = bias[m] (per output row)
// Tile TM x TN, 256 threads = 4 waves arranged WR x WC; per-wave frags FI x FJ.
//
// LDS XOR-swizzled in 16-B chunks: slot (row, cs) holds global chunk
// cs ^ (row & 7); staging permutes the GLOBAL address (global_load_lds dest
// must stay lane-contiguous), reads apply the inverse XOR. Verified R3:
// SQ_LDS_BANK_CONFLICT 3.8e7 -> 0.
template <int TM, int TN, int WR, int WC, typename OutT>
__device__ __forceinline__ void gemm_bt_tile(
    const bf16* __restrict__ A, const bf16* __restrict__ B,
    const float* __restrict__ bias, OutT* __restrict__ C,
    int Kdim, int N, float alpha, int bm, int bn, int bias_mode)
{
    constexpr int FI = TM / (WR * 16);
    constexpr int FJ = TN / (WC * 16);
    __shared__ __attribute__((aligned(16))) bf16 As[TM * BK];
    __shared__ __attribute__((aligned(16))) bf16 Bs[TN * BK];

    const int tid  = threadIdx.x;        // 0..255
    const int lane = tid & 63;
    const int wave = tid >> 6;           // 0..3
    const int wm   = (wave / WC) * (FI * 16);
    const int wn   = (wave % WC) * (FJ * 16);
    const int lr   = lane & 15;          // row-in-16 (A frag) / col-in-16 (B frag)
    const int lkc  = lane >> 4;          // k-chunk index 0..3 (8 bf16 = 16 B each)

    floatx4 acc[FI][FJ] = {};

    const bf16* Ab = A + (size_t)(bm * TM) * Kdim;
    const bf16* Bb = B + (size_t)(bn * TN) * Kdim;

    for (int k0 = 0; k0 < Kdim; k0 += BK) {
        __syncthreads();  // previous tile's compute done before overwrite
#pragma unroll
        for (int p = 0; p < TM * 8 / 256; ++p) {
            const int t   = p * 256 + tid;        // chunk id within As
            const int row = t >> 3;
            const int cg  = (t & 7) ^ (row & 7);  // swizzled global chunk
            __builtin_amdgcn_global_load_lds(
                (const __attribute__((address_space(1))) void*)(Ab + (size_t)row * Kdim + k0 + cg * 8),
                (__attribute__((address_space(3))) void*)(As + t * 8), 16, 0, 0);
        }
#pragma unroll
        for (int p = 0; p < TN * 8 / 256; ++p) {
            const int t   = p * 256 + tid;        // chunk id within Bs
            const int row = t >> 3;
            const int cg  = (t & 7) ^ (row & 7);
            __builtin_amdgcn_global_load_lds(
                (const __attribute__((address_space(1))) void*)(Bb + (size_t)row * Kdim + k0 + cg * 8),
                (__attribute__((address_space(3))) void*)(Bs + t * 8), 16, 0, 0);
        }
        __syncthreads();  // implies s_waitcnt vmcnt(0): staging complete

#pragma unroll
        for (int kk = 0; kk < 2; ++kk) {
            // inverse swizzle: global chunk c = kk*4 + lkc of row r at LDS
            // slot c ^ (r & 7); r & 7 == lr & 7 for all fragment rows.
            const int sw = (((kk << 2) + lkc) ^ (lr & 7)) << 3;
            short8 af[FI], bfr[FJ];
#pragma unroll
            for (int i = 0; i < FI; ++i)
                af[i]  = *(const short8*)(As + (wm + i * 16 + lr) * BK + sw);
#pragma unroll
            for (int j = 0; j < FJ; ++j)
                bfr[j] = *(const short8*)(Bs + (wn + j * 16 + lr) * BK + sw);
#pragma unroll
            for (int i = 0; i < FI; ++i)
#pragma unroll
                for (int j = 0; j < FJ; ++j)
                    acc[i][j] = __builtin_amdgcn_mfma_f32_16x16x32_bf16(
                        af[i], bfr[j], acc[i][j], 0, 0, 0);
        }
    }

    // Epilogue. C/D layout: col = lane&15, row = (lane>>4)*4 + reg   [m89-verified]
    const int rbase = (lane >> 4) << 2;
#pragma unroll
    for (int i = 0; i < FI; ++i) {
#pragma unroll
        for (int j = 0; j < FJ; ++j) {
            const int n = bn * TN + wn + j * 16 + lr;
#pragma unroll
            for (int r = 0; r < 4; ++r) {
                const int m = bm * TM + wm + i * 16 + rbase + r;
                float v = acc[i][j][r] * alpha;
                if (bias_mode == 1)      v += bias[n];
                else if (bias_mode == 2) v += bias[m];
                store_out(&C[(size_t)m * N + n], v);
            }
        }
    }
}

// Fused fp32 -> bf16 convert of x, Wq, Wk, Wv into one contiguous bf16 region.
__global__ __launch_bounds__(256) void cvt_all(
    const float* __restrict__ x, const float* __restrict__ Wq,
    const float* __restrict__ Wk, const float* __restrict__ Wv,
    bf16* __restrict__ dst, int nd4, int dd4)
{
    const int i = blockIdx.x * 256 + threadIdx.x;   // float4 index
    const float* src;
    int off;
    if (i < nd4)                { src = x;  off = i; }
    else if (i < nd4 + dd4)     { src = Wq; off = i - nd4; }
    else if (i < nd4 + 2 * dd4) { src = Wk; off = i - nd4 - dd4; }
    else                        { src = Wv; off = i - nd4 - 2 * dd4; }
    const float4 v = ((const float4*)src)[off];
    bf16 o[4] = {__float2bfloat16(v.x), __float2bfloat16(v.y),
                 __float2bfloat16(v.z), __float2bfloat16(v.w)};
    ((ulong1*)dst)[i] = *(const ulong1*)o;
}

// grid (32,16,3). z=0: Q = xb.Wqb^T + bq  [4096x2048]
//                 z=1: K = xb.Wkb^T + bk  [4096x2048]
//                 z=2: Vt = Wvb.xb^T + bv [2048x4096]  (V produced pre-transposed)
__global__ __launch_bounds__(256) void qkv_gemm(
    const bf16* __restrict__ xb,
    const bf16* __restrict__ Wqb, const float* __restrict__ bq,
    const bf16* __restrict__ Wkb, const float* __restrict__ bk,
    const bf16* __restrict__ Wvb, const float* __restrict__ bv,
    bf16* __restrict__ Q, bf16* __restrict__ Km, bf16* __restrict__ Vt)
{
    const int z = blockIdx.z;
    if (z == 0)
        gemm_bt_tile<128, 128, 2, 2>(xb, Wqb, bq, Q, 2048, 2048, 1.0f, blockIdx.x, blockIdx.y, 1);
    else if (z == 1)
        gemm_bt_tile<128, 128, 2, 2>(xb, Wkb, bk, Km, 2048, 2048, 1.0f, blockIdx.x, blockIdx.y, 1);
    else
        gemm_bt_tile<128, 128, 2, 2>(Wvb, xb, bv, Vt, 2048, 4096, 1.0f, blockIdx.y, blockIdx.x, 2);
}

// grid (32,32): S = (Q.K^T) / sqrt(2048)   [4096x4096], bf16 out
__global__ __launch_bounds__(256) void score_gemm(
    const bf16* __restrict__ Q, const bf16* __restrict__ Km, bf16* __restrict__ S)
{
    gemm_bt_tile<128, 128, 2, 2>(Q, Km, nullptr, S, 2048, 4096, 0.022097086912079608f,
                                 blockIdx.x, blockIdx.y, 0);
}

// grid (64,16): out = S.(Vt)^T = S.V   [4096x2048], fp32 out
// 64x128 tile: 1024 blocks, 24 KB LDS -> 6 blocks/CU = 24 waves/CU
// (128x128 gave only 512 blocks = 2 blocks/CU = 8 waves/CU: no latency hiding)
__global__ __launch_bounds__(256) void ctx_gemm(
    const bf16* __restrict__ S, const bf16* __restrict__ Vt, float* __restrict__ out)
{
    gemm_bt_tile<64, 128, 1, 4>(S, Vt, nullptr, out, 4096, 2048, 1.0f,
                                blockIdx.x, blockIdx.y, 0);
}

extern "C" void kernel_launch(void* const* d_in, const int* in_sizes, int n_in,
                              void* d_out, int out_size, void* d_ws, size_t ws_size,
                              hipStream_t stream)
{
    const float* x  = (const float*)d_in[0];
    const float* Wq = (const float*)d_in[1];
    const float* bq = (const float*)d_in[2];
    const float* Wk = (const float*)d_in[3];
    const float* bk = (const float*)d_in[4];
    const float* Wv = (const float*)d_in[5];
    const float* bv = (const float*)d_in[6];
    float* out = (float*)d_out;

    const size_t ND = (size_t)4096 * 2048;   // x elems
    const size_t DD = (size_t)2048 * 2048;   // W elems

    // Workspace (bf16 elems): xb(8M) Wqb Wkb Wvb(4M ea) Q K Vt(8M ea) S(16M) = 120 MB
    bf16* xb  = (bf16*)d_ws;
    bf16* Wqb = xb  + ND;
    bf16* Wkb = Wqb + DD;
    bf16* Wvb = Wkb + DD;
    bf16* Q   = Wvb + DD;
    bf16* Km  = Q   + ND;
    bf16* Vt  = Km  + ND;
    bf16* S   = Vt  + ND;   // 4096*4096

    const int nd4 = (int)(ND / 4), dd4 = (int)(DD / 4);
    cvt_all<<<(nd4 + 3 * dd4) / 256, 256, 0, stream>>>(x, Wq, Wk, Wv, xb, nd4, dd4);

    qkv_gemm<<<dim3(32, 16, 3), 256, 0, stream>>>(xb, Wqb, bq, Wkb, bk, Wvb, bv, Q, Km, Vt);
    score_gemm<<<dim3(32, 32), 256, 0, stream>>>(Q, Km, S);
    ctx_gemm<<<dim3(64, 16), 256, 0, stream>>>(S, Vt, out);
}

// Round 5
// 335.286 us; speedup vs baseline: 1.3970x; 1.1929x over previous
//
#include <hip/hip_runtime.h>
#include <hip/hip_bf16.h>

typedef __hip_bfloat16 bf16;
typedef __attribute__((ext_vector_type(8))) short short8;
typedef __attribute__((ext_vector_type(4))) float floatx4;

#define BK 64

__device__ __forceinline__ void store_out(bf16* p, float v)  { *p = __float2bfloat16(v); }
__device__ __forceinline__ void store_out(float* p, float v) { *p = v; }

// C[M,N] = alpha * (A[M,K] . B[N,K]^T) + bias   (A,B bf16; C is OutT)
// bias_mode: 0 = none, 1 = bias[n] (per output col), 2 = bias[m] (per output row)
// Tile TM x TN, 256 threads = 4 waves arranged WR x WC; per-wave frags FI x FJ.
//
// LDS XOR-swizzled in 16-B chunks: slot (row, cs) holds global chunk
// cs ^ (row & 7); staging permutes the GLOBAL address (global_load_lds dest
// must stay lane-contiguous), reads apply the inverse XOR. Verified R3:
// SQ_LDS_BANK_CONFLICT 3.8e7 -> 0.
template <int TM, int TN, int WR, int WC, typename OutT>
__device__ __forceinline__ void gemm_bt_tile(
    const bf16* __restrict__ A, const bf16* __restrict__ B,
    const float* __restrict__ bias, OutT* __restrict__ C,
    int Kdim, int N, float alpha, int bm, int bn, int bias_mode)
{
    constexpr int FI = TM / (WR * 16);
    constexpr int FJ = TN / (WC * 16);
    __shared__ __attribute__((aligned(16))) bf16 As[TM * BK];
    __shared__ __attribute__((aligned(16))) bf16 Bs[TN * BK];

    const int tid  = threadIdx.x;        // 0..255
    const int lane = tid & 63;
    const int wave = tid >> 6;           // 0..3
    const int wm   = (wave / WC) * (FI * 16);
    const int wn   = (wave % WC) * (FJ * 16);
    const int lr   = lane & 15;          // row-in-16 (A frag) / col-in-16 (B frag)
    const int lkc  = lane >> 4;          // k-chunk index 0..3 (8 bf16 = 16 B each)

    floatx4 acc[FI][FJ] = {};

    const bf16* Ab = A + (size_t)(bm * TM) * Kdim;
    const bf16* Bb = B + (size_t)(bn * TN) * Kdim;

    for (int k0 = 0; k0 < Kdim; k0 += BK) {
        __syncthreads();  // previous tile's compute done before overwrite
#pragma unroll
        for (int p = 0; p < TM * 8 / 256; ++p) {
            const int t   = p * 256 + tid;        // chunk id within As
            const int row = t >> 3;
            const int cg  = (t & 7) ^ (row & 7);  // swizzled global chunk
            __builtin_amdgcn_global_load_lds(
                (const __attribute__((address_space(1))) void*)(Ab + (size_t)row * Kdim + k0 + cg * 8),
                (__attribute__((address_space(3))) void*)(As + t * 8), 16, 0, 0);
        }
#pragma unroll
        for (int p = 0; p < TN * 8 / 256; ++p) {
            const int t   = p * 256 + tid;        // chunk id within Bs
            const int row = t >> 3;
            const int cg  = (t & 7) ^ (row & 7);
            __builtin_amdgcn_global_load_lds(
                (const __attribute__((address_space(1))) void*)(Bb + (size_t)row * Kdim + k0 + cg * 8),
                (__attribute__((address_space(3))) void*)(Bs + t * 8), 16, 0, 0);
        }
        __syncthreads();  // implies s_waitcnt vmcnt(0): staging complete

#pragma unroll
        for (int kk = 0; kk < 2; ++kk) {
            // inverse swizzle: global chunk c = kk*4 + lkc of row r at LDS
            // slot c ^ (r & 7); r & 7 == lr & 7 for all fragment rows.
            const int sw = (((kk << 2) + lkc) ^ (lr & 7)) << 3;
            short8 af[FI], bfr[FJ];
#pragma unroll
            for (int i = 0; i < FI; ++i)
                af[i]  = *(const short8*)(As + (wm + i * 16 + lr) * BK + sw);
#pragma unroll
            for (int j = 0; j < FJ; ++j)
                bfr[j] = *(const short8*)(Bs + (wn + j * 16 + lr) * BK + sw);
#pragma unroll
            for (int i = 0; i < FI; ++i)
#pragma unroll
                for (int j = 0; j < FJ; ++j)
                    acc[i][j] = __builtin_amdgcn_mfma_f32_16x16x32_bf16(
                        af[i], bfr[j], acc[i][j], 0, 0, 0);
        }
    }

    // Epilogue. C/D layout: col = lane&15, row = (lane>>4)*4 + reg   [m89-verified]
    const int rbase = (lane >> 4) << 2;
#pragma unroll
    for (int i = 0; i < FI; ++i) {
#pragma unroll
        for (int j = 0; j < FJ; ++j) {
            const int n = bn * TN + wn + j * 16 + lr;
#pragma unroll
            for (int r = 0; r < 4; ++r) {
                const int m = bm * TM + wm + i * 16 + rbase + r;
                float v = acc[i][j][r] * alpha;
                if (bias_mode == 1)      v += bias[n];
                else if (bias_mode == 2) v += bias[m];
                store_out(&C[(size_t)m * N + n], v);
            }
        }
    }
}

// Fused fp32 -> bf16 convert of x, Wq, Wk, Wv into one contiguous bf16 region.
__global__ __launch_bounds__(256) void cvt_all(
    const float* __restrict__ x, const float* __restrict__ Wq,
    const float* __restrict__ Wk, const float* __restrict__ Wv,
    bf16* __restrict__ dst, int nd4, int dd4)
{
    const int i = blockIdx.x * 256 + threadIdx.x;   // float4 index
    const float* src;
    int off;
    if (i < nd4)                { src = x;  off = i; }
    else if (i < nd4 + dd4)     { src = Wq; off = i - nd4; }
    else if (i < nd4 + 2 * dd4) { src = Wk; off = i - nd4 - dd4; }
    else                        { src = Wv; off = i - nd4 - 2 * dd4; }
    const float4 v = ((const float4*)src)[off];
    bf16 o[4] = {__float2bfloat16(v.x), __float2bfloat16(v.y),
                 __float2bfloat16(v.z), __float2bfloat16(v.w)};
    ((ulong1*)dst)[i] = *(const ulong1*)o;
}

// ASSOCIATIVITY REWRITE (no softmax => fully linear):
//   context = (Q.K^T/sqrt(D)).V = Q.(K^T.V)/sqrt(D)
// K^T.V is only [2048x2048]: attention FLOPs halve (137 -> 69 GF) and the
// 32 MB score matrix disappears entirely.
//
// grid (32,16,3). z=0: Q  = xb.Wqb^T + bq  [4096x2048]
//                 z=1: Kt = Wkb.xb^T + bk  [2048x4096]  (K pre-transposed)
//                 z=2: Vt = Wvb.xb^T + bv  [2048x4096]  (V pre-transposed)
__global__ __launch_bounds__(256) void qkv_gemm(
    const bf16* __restrict__ xb,
    const bf16* __restrict__ Wqb, const float* __restrict__ bq,
    const bf16* __restrict__ Wkb, const float* __restrict__ bk,
    const bf16* __restrict__ Wvb, const float* __restrict__ bv,
    bf16* __restrict__ Q, bf16* __restrict__ Kt, bf16* __restrict__ Vt)
{
    const int z = blockIdx.z;
    if (z == 0)
        gemm_bt_tile<128, 128, 2, 2>(xb, Wqb, bq, Q, 2048, 2048, 1.0f, blockIdx.x, blockIdx.y, 1);
    else if (z == 1)
        gemm_bt_tile<128, 128, 2, 2>(Wkb, xb, bk, Kt, 2048, 4096, 1.0f, blockIdx.y, blockIdx.x, 2);
    else
        gemm_bt_tile<128, 128, 2, 2>(Wvb, xb, bv, Vt, 2048, 4096, 1.0f, blockIdx.y, blockIdx.x, 2);
}

// grid (16,32): U = Vt.Kt^T   [2048x2048], K-dim 4096, bf16 out
//   U[n,k] = sum_s V[s,n]K[s,k]  ( = (V^T.K) )
// 128x64 tile -> 512 blocks (2/CU); 128x128 would give only 256 (1/CU).
__global__ __launch_bounds__(256) void u_gemm(
    const bf16* __restrict__ Vt, const bf16* __restrict__ Kt, bf16* __restrict__ U)
{
    gemm_bt_tile<128, 64, 2, 2>(Vt, Kt, nullptr, U, 4096, 2048, 1.0f,
                                blockIdx.x, blockIdx.y, 0);
}

// grid (32,16): out = (Q.U^T)/sqrt(D)   [4096x2048], fp32 out
//   out[m,n] = (1/sqrt(D)) sum_k Q[m,k]U[n,k] = sum_s scores[m,s]V[s,n]
__global__ __launch_bounds__(256) void out_gemm(
    const bf16* __restrict__ Q, const bf16* __restrict__ U, float* __restrict__ out)
{
    gemm_bt_tile<128, 128, 2, 2>(Q, U, nullptr, out, 2048, 2048,
                                 0.022097086912079608f, blockIdx.x, blockIdx.y, 0);
}

extern "C" void kernel_launch(void* const* d_in, const int* in_sizes, int n_in,
                              void* d_out, int out_size, void* d_ws, size_t ws_size,
                              hipStream_t stream)
{
    const float* x  = (const float*)d_in[0];
    const float* Wq = (const float*)d_in[1];
    const float* bq = (const float*)d_in[2];
    const float* Wk = (const float*)d_in[3];
    const float* bk = (const float*)d_in[4];
    const float* Wv = (const float*)d_in[5];
    const float* bv = (const float*)d_in[6];
    float* out = (float*)d_out;

    const size_t ND = (size_t)4096 * 2048;   // x elems
    const size_t DD = (size_t)2048 * 2048;   // W elems

    // Workspace (bf16 elems): xb(16MB) Wqb/Wkb/Wvb(8MB ea) Q(16MB) Kt(16MB)
    // Vt(16MB) U(8MB) = 96 MB total
    bf16* xb  = (bf16*)d_ws;
    bf16* Wqb = xb  + ND;
    bf16* Wkb = Wqb + DD;
    bf16* Wvb = Wkb + DD;
    bf16* Q   = Wvb + DD;
    bf16* Kt  = Q   + ND;
    bf16* Vt  = Kt  + ND;
    bf16* U   = Vt  + ND;   // 2048*2048

    const int nd4 = (int)(ND / 4), dd4 = (int)(DD / 4);
    cvt_all<<<(nd4 + 3 * dd4) / 256, 256, 0, stream>>>(x, Wq, Wk, Wv, xb, nd4, dd4);

    qkv_gemm<<<dim3(32, 16, 3), 256, 0, stream>>>(xb, Wqb, bq, Wkb, bk, Wvb, bv, Q, Kt, Vt);
    u_gemm<<<dim3(16, 32), 256, 0, stream>>>(Vt, Kt, U);
    out_gemm<<<dim3(32, 16), 256, 0, stream>>>(Q, U, out);
}